// Round 15
// baseline (5790.599 us; speedup 1.0000x reference)
//
#include <hip/hip_runtime.h>
#include <cstdint>

typedef __attribute__((ext_vector_type(4))) float f32x4;
typedef __attribute__((ext_vector_type(8))) short s16x8;
typedef __attribute__((ext_vector_type(8))) unsigned short u16x8;
typedef __attribute__((ext_vector_type(4))) unsigned short u16x4;

#define DEVI __device__ __forceinline__

namespace {

constexpr int B = 32, L = 2048, D = 1024, H = 16;
constexpr int CHUNK = 128, MEM = 64, T = 192;
constexpr int NC = 16;

DEVI unsigned short f2bf(float f) {
  unsigned x = __builtin_bit_cast(unsigned, f);
  return (unsigned short)((x + 0x7fffu + ((x >> 16) & 1u)) >> 16);
}
DEVI float bf2f(unsigned short u) {
  return __builtin_bit_cast(float, (unsigned)u << 16);
}

typedef const __attribute__((address_space(1))) unsigned char ga_t;
typedef __attribute__((address_space(3))) unsigned char la_t;

DEVI void gload16(const void* g, void* l) {
  __builtin_amdgcn_global_load_lds((ga_t*)g, (la_t*)l, 16, 0, 0);
}

__global__ void k_cvt(const float* __restrict__ in, unsigned short* __restrict__ out, int n) {
  int i = blockIdx.x * 256 + threadIdx.x;
  if (i < n) out[i] = f2bf(in[i]);
}

__global__ void k_copy_mem(const float* __restrict__ src, float* __restrict__ dst) {
  int i = blockIdx.x * 256 + threadIdx.x;
  dst[i] = src[i];
}

// Unified pre-step kernel: one row per block (grid B*T).
__global__ __launch_bounds__(256) void k_pre(
    const unsigned short* __restrict__ p4, float* __restrict__ z,
    const float* __restrict__ gb, float* __restrict__ memb,
    const float* __restrict__ mem_init, const float* __restrict__ pos,
    const float* __restrict__ embP, const float* __restrict__ embS,
    const int* __restrict__ ipr, const int* __restrict__ isk,
    const float* __restrict__ gg, const float* __restrict__ bb,
    unsigned short* __restrict__ lnout, int t)
{
  const int row = blockIdx.x;            // 0 .. B*T-1
  const int b = row / T, i = row % T;
  const int tid = threadIdx.x;
  const int c = tid * 4;
  f32x4 v;
  if (i < MEM) {
    const int idx = b * MEM + i;
    f32x4 r;
    if (t == 0) {
      r = *reinterpret_cast<const f32x4*>(&mem_init[(size_t)i * D + c]);
    } else {
      const size_t MN = (size_t)B * MEM * D;
      f32x4 sacc = *reinterpret_cast<const f32x4*>(&gb[c]);
      #pragma unroll
      for (int k = 0; k < 4; ++k) {
        const u16x4 pk = *reinterpret_cast<const u16x4*>(&p4[k * MN + (size_t)idx * D + c]);
        #pragma unroll
        for (int e = 0; e < 4; ++e) sacc[e] += bf2f(pk[e]);
      }
      const f32x4 cand = *reinterpret_cast<const f32x4*>(&z[(size_t)row * D + c]);
      const f32x4 mo   = *reinterpret_cast<const f32x4*>(&memb[(size_t)idx * D + c]);
      #pragma unroll
      for (int e = 0; e < 4; ++e) {
        const float g = 1.0f / (1.0f + __expf(-sacc[e]));
        r[e] = (t - 1 == 0) ? cand[e] : g * cand[e] + (1.0f - g) * mo[e];
      }
    }
    *reinterpret_cast<f32x4*>(&memb[((size_t)b * MEM + i) * D + c]) = r;
    const f32x4 pp = *reinterpret_cast<const f32x4*>(&pos[i * D + c]);
    #pragma unroll
    for (int e = 0; e < 4; ++e) v[e] = r[e] + pp[e];
  } else {
    const int j = t * CHUNK + (i - MEM);
    const int pi = ipr[b * L + j], si = isk[b * L + j];
    const f32x4 ep = *reinterpret_cast<const f32x4*>(&embP[(size_t)pi * D + c]);
    const f32x4 es = *reinterpret_cast<const f32x4*>(&embS[(size_t)si * D + c]);
    const f32x4 pp = *reinterpret_cast<const f32x4*>(&pos[i * D + c]);
    #pragma unroll
    for (int e = 0; e < 4; ++e) v[e] = ep[e] + es[e] + pp[e];
  }
  *reinterpret_cast<f32x4*>(&z[(size_t)row * D + c]) = v;

  float s = v[0] + v[1] + v[2] + v[3];
  float s2 = v[0]*v[0] + v[1]*v[1] + v[2]*v[2] + v[3]*v[3];
  #pragma unroll
  for (int m = 1; m < 64; m <<= 1) { s += __shfl_xor(s, m, 64); s2 += __shfl_xor(s2, m, 64); }
  __shared__ float ps[4], ps2[4];
  const int wid = tid >> 6;
  if ((tid & 63) == 0) { ps[wid] = s; ps2[wid] = s2; }
  __syncthreads();
  s  = ps[0] + ps[1] + ps[2] + ps[3];
  s2 = ps2[0] + ps2[1] + ps2[2] + ps2[3];
  const float mu  = s * (1.0f / 1024.0f);
  const float var = s2 * (1.0f / 1024.0f) - mu * mu;
  const float rs  = rsqrtf(var + 1e-5f);
  u16x4 o;
  #pragma unroll
  for (int e = 0; e < 4; ++e)
    o[e] = f2bf((v[e] - mu) * rs * gg[c + e] + bb[c + e]);
  *reinterpret_cast<u16x4*>(&lnout[(size_t)row * D + c]) = o;
}

// LN_f with WO split-K reduce fused (wave-per-row, 4 rows/block).
__global__ __launch_bounds__(256) void k_ln2(
    const float* __restrict__ gg, const float* __restrict__ bb,
    float* __restrict__ z, unsigned short* __restrict__ zcb,
    unsigned short* __restrict__ lnout,
    const unsigned short* __restrict__ pp, const float* __restrict__ bo)
{
  const int tid = threadIdx.x, lane = tid & 63, wid = tid >> 6;
  const int row = blockIdx.x * 4 + wid;      // 0 .. B*T-1
  const int i = row % T;
  const int c0 = lane * 4;
  const size_t MN = (size_t)B * T * D;

  float v[16];
  #pragma unroll
  for (int k = 0; k < 4; ++k) {
    const int c = k * 256 + c0;
    const f32x4 zz = *reinterpret_cast<const f32x4*>(&z[(size_t)row * D + c]);
    const u16x4 p0 = *reinterpret_cast<const u16x4*>(&pp[(size_t)row * D + c]);
    const u16x4 p1 = *reinterpret_cast<const u16x4*>(&pp[MN + (size_t)row * D + c]);
    const f32x4 bv = *reinterpret_cast<const f32x4*>(&bo[c]);
    #pragma unroll
    for (int e = 0; e < 4; ++e)
      v[k * 4 + e] = zz[e] + bf2f(p0[e]) + bf2f(p1[e]) + bv[e];
  }
  float s = 0.f, s2 = 0.f;
  #pragma unroll
  for (int e = 0; e < 16; ++e) { s += v[e]; s2 += v[e] * v[e]; }
  #pragma unroll
  for (int m = 1; m < 64; m <<= 1) { s += __shfl_xor(s, m, 64); s2 += __shfl_xor(s2, m, 64); }
  const float mu  = s * (1.0f / 1024.0f);
  const float var = s2 * (1.0f / 1024.0f) - mu * mu;
  const float rs  = rsqrtf(var + 1e-5f);
  if (i < MEM) {
    #pragma unroll
    for (int k = 0; k < 4; ++k) {
      f32x4 zz = {v[k*4+0], v[k*4+1], v[k*4+2], v[k*4+3]};
      *reinterpret_cast<f32x4*>(&z[(size_t)row * D + k * 256 + c0]) = zz;
    }
  } else {
    #pragma unroll
    for (int k = 0; k < 4; ++k) {
      const int c = k * 256 + c0;
      u16x4 o;
      #pragma unroll
      for (int e = 0; e < 4; ++e) o[e] = f2bf(v[k * 4 + e]);
      *reinterpret_cast<u16x4*>(&zcb[(size_t)row * D + c]) = o;
    }
  }
  #pragma unroll
  for (int k = 0; k < 4; ++k) {
    const int c = k * 256 + c0;
    u16x4 o;
    #pragma unroll
    for (int e = 0; e < 4; ++e)
      o[e] = f2bf((v[k * 4 + e] - mu) * rs * gg[c + e] + bb[c + e]);
    *reinterpret_cast<u16x4*>(&lnout[(size_t)row * D + c]) = o;
  }
}

struct GArgs {
  const unsigned short* A; const unsigned short* W; const float* bias;
  unsigned short* outb; float* z; float* outf; unsigned short* candb; float* mem;
  int M, N, K, t;
};

// ---- 2-phase dbuf 128x128 bf16 GEMM (proven) ----
// EPI 0: bf16 out   1: relu->bf16   9: bf16 partial store (split-K, no bias)
template<int EPI, int SPLITK>
__global__ __launch_bounds__(256) void k_gemmp(GArgs a)
{
  __shared__ __align__(16) unsigned short Al[2][128 * 32];
  __shared__ __align__(16) unsigned short Bl[2][128 * 32];
  const int tid = threadIdx.x;
  const int lane = tid & 63, wid = tid >> 6;
  const int gx = gridDim.x;
  const int nwg = gx * gridDim.y;
  const int f = blockIdx.y * gx + blockIdx.x;
  const int tile = (f & 7) * (nwg >> 3) + (f >> 3);
  const int brow = (tile / gx) * 128, bcol = (tile % gx) * 128;
  const int wr = wid >> 1, wc = wid & 1;
  const int c0 = lane & 15, g4 = lane >> 4;
  const int K = a.K;
  const int Ks = K / SPLITK;
  const int kbase = blockIdx.z * Ks;

  const int r0 = tid >> 2, oc8 = (tid & 3) * 8;
  const int dst0 = wid * 512, dst1 = 2048 + wid * 512;   // shorts

  f32x4 acc[4][4] = {};

  const unsigned short* __restrict__ Ag = a.A;
  const unsigned short* __restrict__ Wg = a.W;

  auto stage = [&](int t1, int buf) {
    const int kb = kbase + t1 * 32;
    gload16(&Ag[(size_t)(brow + r0) * K + kb + oc8],      &Al[buf][dst0]);
    gload16(&Ag[(size_t)(brow + 64 + r0) * K + kb + oc8], &Al[buf][dst1]);
    gload16(&Wg[(size_t)(bcol + r0) * K + kb + oc8],      &Bl[buf][dst0]);
    gload16(&Wg[(size_t)(bcol + 64 + r0) * K + kb + oc8], &Bl[buf][dst1]);
  };

  stage(0, 0);
  const int nt = Ks >> 5;
  int cur = 0;
  for (int t = 0; t < nt; ++t) {
    __syncthreads();
    if (t + 1 < nt) stage(t + 1, cur ^ 1);
    s16x8 af[4], bf[4];
    #pragma unroll
    for (int m = 0; m < 4; ++m)
      af[m] = *reinterpret_cast<const s16x8*>(&Al[cur][(wr * 64 + m * 16 + c0) * 32 + g4 * 8]);
    #pragma unroll
    for (int n = 0; n < 4; ++n)
      bf[n] = *reinterpret_cast<const s16x8*>(&Bl[cur][(wc * 64 + n * 16 + c0) * 32 + g4 * 8]);
    #pragma unroll
    for (int m = 0; m < 4; ++m)
      #pragma unroll
      for (int n = 0; n < 4; ++n)
        acc[m][n] = __builtin_amdgcn_mfma_f32_16x16x32_bf16(af[m], bf[n], acc[m][n], 0, 0, 0);
    cur ^= 1;
  }

  #pragma unroll
  for (int m = 0; m < 4; ++m) {
    #pragma unroll
    for (int n = 0; n < 4; ++n) {
      const int col = bcol + wc * 64 + n * 16 + c0;
      float bv = 0.f;
      if constexpr (EPI != 9) bv = a.bias[col];
      #pragma unroll
      for (int j = 0; j < 4; ++j) {
        const int row = brow + wr * 64 + m * 16 + g4 * 4 + j;
        float v = acc[m][n][j] + bv;
        if constexpr (EPI == 0) {
          a.outb[(size_t)row * a.N + col] = f2bf(v);
        } else if constexpr (EPI == 1) {
          a.outb[(size_t)row * a.N + col] = f2bf(v > 0.f ? v : 0.f);
        } else if constexpr (EPI == 9) {
          a.outb[(size_t)blockIdx.z * a.M * a.N + (size_t)row * a.N + col] = f2bf(v);
        }
      }
    }
  }
}

// ---- WIDE 2-phase dbuf 128x256 bf16 GEMM: 4 waves, 64x128 per wave ----
// Per K-tile per wave: 12 ds_read_b128 for 32 MFMA (vs 8:16) -> less LDS-bound.
// Same __syncthreads 2-phase schedule as k_gemmp. EPI 0: bf16; 1: relu->bf16.
template<int EPI>
__global__ __launch_bounds__(256) void k_gemmw(GArgs a)
{
  __shared__ __align__(16) unsigned short Al[2][128 * 32];   // 16 KB
  __shared__ __align__(16) unsigned short Bl[2][256 * 32];   // 32 KB
  const int tid = threadIdx.x;
  const int lane = tid & 63, wid = tid >> 6;
  const int gx = gridDim.x;
  const int nwg = gx * gridDim.y;
  const int f = blockIdx.y * gx + blockIdx.x;
  const int tile = (f & 7) * (nwg >> 3) + (f >> 3);
  const int brow = (tile / gx) * 128, bcol = (tile % gx) * 256;
  const int wr = wid >> 1, wc = wid & 1;
  const int c0 = lane & 15, g4 = lane >> 4;
  const int K = a.K;

  const int r0 = tid >> 2, oc8 = (tid & 3) * 8;
  const int dst = wid * 512;            // shorts, per-64-row block

  f32x4 acc[4][8] = {};

  const unsigned short* __restrict__ Ag = a.A;
  const unsigned short* __restrict__ Wg = a.W;

  auto stage = [&](int t1, int buf) {
    const int kb = t1 * 32;
    gload16(&Ag[(size_t)(brow + r0) * K + kb + oc8],        &Al[buf][dst]);
    gload16(&Ag[(size_t)(brow + 64 + r0) * K + kb + oc8],   &Al[buf][2048 + dst]);
    gload16(&Wg[(size_t)(bcol + r0) * K + kb + oc8],        &Bl[buf][dst]);
    gload16(&Wg[(size_t)(bcol + 64 + r0) * K + kb + oc8],   &Bl[buf][2048 + dst]);
    gload16(&Wg[(size_t)(bcol + 128 + r0) * K + kb + oc8],  &Bl[buf][4096 + dst]);
    gload16(&Wg[(size_t)(bcol + 192 + r0) * K + kb + oc8],  &Bl[buf][6144 + dst]);
  };

  stage(0, 0);
  const int nt = K >> 5;
  int cur = 0;
  for (int t = 0; t < nt; ++t) {
    __syncthreads();
    if (t + 1 < nt) stage(t + 1, cur ^ 1);
    s16x8 af[4], bf[8];
    #pragma unroll
    for (int m = 0; m < 4; ++m)
      af[m] = *reinterpret_cast<const s16x8*>(&Al[cur][(wr * 64 + m * 16 + c0) * 32 + g4 * 8]);
    #pragma unroll
    for (int n = 0; n < 8; ++n)
      bf[n] = *reinterpret_cast<const s16x8*>(&Bl[cur][(wc * 128 + n * 16 + c0) * 32 + g4 * 8]);
    #pragma unroll
    for (int m = 0; m < 4; ++m)
      #pragma unroll
      for (int n = 0; n < 8; ++n)
        acc[m][n] = __builtin_amdgcn_mfma_f32_16x16x32_bf16(af[m], bf[n], acc[m][n], 0, 0, 0);
    cur ^= 1;
  }

  #pragma unroll
  for (int m = 0; m < 4; ++m) {
    #pragma unroll
    for (int n = 0; n < 8; ++n) {
      const int col = bcol + wc * 128 + n * 16 + c0;
      const float bv = a.bias[col];
      #pragma unroll
      for (int j = 0; j < 4; ++j) {
        const int row = brow + wr * 64 + m * 16 + g4 * 4 + j;
        float v = acc[m][n][j] + bv;
        if constexpr (EPI == 0) {
          a.outb[(size_t)row * a.N + col] = f2bf(v);
        } else {
          a.outb[(size_t)row * a.N + col] = f2bf(v > 0.f ? v : 0.f);
        }
      }
    }
  }
}

// FFN2 reduce: v = p0+p1+bias (bf16 partials);
// mem rows: zv = z + v -> z, candb; chunk rows: zv = zcb + v -> d_out.
__global__ __launch_bounds__(256) void k_red2(
    const unsigned short* __restrict__ p, float* __restrict__ z,
    const unsigned short* __restrict__ zcb, const float* __restrict__ bias,
    float* __restrict__ out, unsigned short* __restrict__ candb, int t)
{
  const int row = blockIdx.x;            // 0 .. B*T-1
  const int b = row / T, i = row % T;
  const int c = threadIdx.x * 4;
  const size_t MN = (size_t)B * T * D;
  const u16x4 p0 = *reinterpret_cast<const u16x4*>(&p[(size_t)row * D + c]);
  const u16x4 p1 = *reinterpret_cast<const u16x4*>(&p[MN + (size_t)row * D + c]);
  const f32x4 bb = *reinterpret_cast<const f32x4*>(&bias[c]);
  f32x4 zv;
  if (i < MEM) {
    const f32x4 zz = *reinterpret_cast<const f32x4*>(&z[(size_t)row * D + c]);
    u16x4 o;
    #pragma unroll
    for (int e = 0; e < 4; ++e) {
      zv[e] = zz[e] + bf2f(p0[e]) + bf2f(p1[e]) + bb[e];
      o[e] = f2bf(zv[e]);
    }
    *reinterpret_cast<f32x4*>(&z[(size_t)row * D + c]) = zv;
    *reinterpret_cast<u16x4*>(&candb[((size_t)b * MEM + i) * D + c]) = o;
  } else {
    const u16x4 zz = *reinterpret_cast<const u16x4*>(&zcb[(size_t)row * D + c]);
    #pragma unroll
    for (int e = 0; e < 4; ++e)
      zv[e] = bf2f(zz[e]) + bf2f(p0[e]) + bf2f(p1[e]) + bb[e];
    *reinterpret_cast<f32x4*>(&out[((size_t)b * L + t * CHUNK + (i - MEM)) * D + c]) = zv;
  }
}

// Plain gate reduce (final step only): writes memb.
__global__ __launch_bounds__(256) void k_redg(
    const unsigned short* __restrict__ p, const float* __restrict__ z,
    const float* __restrict__ gb, float* __restrict__ memb, int t)
{
  const int row = blockIdx.x;            // 0 .. B*MEM-1
  const int b = row >> 6, i = row & 63;
  const int c = threadIdx.x * 4;
  const size_t MN = (size_t)B * MEM * D;
  f32x4 s = *reinterpret_cast<const f32x4*>(&gb[c]);
  #pragma unroll
  for (int k = 0; k < 4; ++k) {
    const u16x4 pk = *reinterpret_cast<const u16x4*>(&p[k * MN + (size_t)row * D + c]);
    #pragma unroll
    for (int e = 0; e < 4; ++e) s[e] += bf2f(pk[e]);
  }
  const f32x4 cand = *reinterpret_cast<const f32x4*>(&z[((size_t)b * T + i) * D + c]);
  f32x4 mo = *reinterpret_cast<f32x4*>(&memb[(size_t)row * D + c]);
  f32x4 r;
  #pragma unroll
  for (int e = 0; e < 4; ++e) {
    const float g = 1.0f / (1.0f + __expf(-s[e]));
    r[e] = (t == 0) ? cand[e] : g * cand[e] + (1.0f - g) * mo[e];
  }
  *reinterpret_cast<f32x4*>(&memb[(size_t)row * D + c]) = r;
}

// One workgroup per (b,h). qkv: [B*T][3072] bf16 (q|k|v each H*64 cols).
__global__ __launch_bounds__(256) void k_attn(const unsigned short* __restrict__ qkv,
                                              unsigned short* __restrict__ attno)
{
  __shared__ unsigned short Ks[192 * 64];
  __shared__ unsigned short Vt[64 * 192];
  __shared__ unsigned short Pl[4][16 * 200];
  const int tid = threadIdx.x, lane = tid & 63, wid = tid >> 6;
  const int b = blockIdx.x >> 4, h = blockIdx.x & 15;
  const size_t base = (size_t)b * T * 3072 + h * 64;

  #pragma unroll
  for (int it = 0; it < 6; ++it) {
    const int cidx = tid + it * 256;
    const int key = cidx >> 3, hb = cidx & 7;
    const u16x8 kv = *reinterpret_cast<const u16x8*>(&qkv[base + (size_t)key * 3072 + 1024 + hb * 8]);
    *reinterpret_cast<u16x8*>(&Ks[key * 64 + ((hb ^ (key & 7)) * 8)]) = kv;
    const u16x8 vv = *reinterpret_cast<const u16x8*>(&qkv[base + (size_t)key * 3072 + 2048 + hb * 8]);
    #pragma unroll
    for (int e = 0; e < 8; ++e) {
      const int hd = hb * 8 + e;
      Vt[hd * 192 + (((key >> 3) + hd) % 24) * 8 + (key & 7)] = vv[e];
    }
  }
  __syncthreads();

  const int c0 = lane & 15, g4 = lane >> 4;
  for (int qb = wid; qb < 12; qb += 4) {
    s16x8 qf[2];
    #pragma unroll
    for (int kk = 0; kk < 2; ++kk)
      qf[kk] = *reinterpret_cast<const s16x8*>(&qkv[base + (size_t)(qb * 16 + c0) * 3072 + kk * 32 + g4 * 8]);
    f32x4 sc[12];
    __builtin_amdgcn_s_setprio(1);
    #pragma unroll
    for (int cb = 0; cb < 12; ++cb) {
      f32x4 s4 = {};
      #pragma unroll
      for (int kk = 0; kk < 2; ++kk) {
        const s16x8 kf = *reinterpret_cast<const s16x8*>(
            &Ks[(cb * 16 + c0) * 64 + (((kk * 4 + g4) ^ (c0 & 7)) * 8)]);
        s4 = __builtin_amdgcn_mfma_f32_16x16x32_bf16(qf[kk], kf, s4, 0, 0, 0);
      }
      sc[cb] = s4;
    }
    __builtin_amdgcn_s_setprio(0);
    #pragma unroll
    for (int j = 0; j < 4; ++j) {
      const int qi = qb * 16 + g4 * 4 + j;
      float mj = -1e30f;
      #pragma unroll
      for (int cb = 0; cb < 12; ++cb) {
        const int kj = cb * 16 + c0;
        float sv = sc[cb][j] * 0.125f;
        if (qi >= MEM && kj > qi) sv = -1e30f;
        sc[cb][j] = sv;
        mj = fmaxf(mj, sv);
      }
      #pragma unroll
      for (int msk = 1; msk <= 8; msk <<= 1) mj = fmaxf(mj, __shfl_xor(mj, msk, 64));
      float sum = 0.f;
      #pragma unroll
      for (int cb = 0; cb < 12; ++cb) {
        const float p = exp2f((sc[cb][j] - mj) * 1.44269504f);
        sc[cb][j] = p;
        sum += p;
      }
      #pragma unroll
      for (int msk = 1; msk <= 8; msk <<= 1) sum += __shfl_xor(sum, msk, 64);
      const float rin = 1.0f / sum;
      #pragma unroll
      for (int cb = 0; cb < 12; ++cb)
        Pl[wid][(g4 * 4 + j) * 200 + cb * 16 + c0] = f2bf(sc[cb][j] * rin);
    }
    #pragma unroll
    for (int cb2 = 0; cb2 < 4; ++cb2) {
      f32x4 ao = {};
      const int hd = cb2 * 16 + c0;
      __builtin_amdgcn_s_setprio(1);
      #pragma unroll
      for (int kk = 0; kk < 6; ++kk) {
        const int k0 = kk * 32 + g4 * 8;
        const s16x8 pf = *reinterpret_cast<const s16x8*>(&Pl[wid][c0 * 200 + k0]);
        const s16x8 vf = *reinterpret_cast<const s16x8*>(&Vt[hd * 192 + (((k0 >> 3) + hd) % 24) * 8]);
        ao = __builtin_amdgcn_mfma_f32_16x16x32_bf16(pf, vf, ao, 0, 0, 0);
      }
      __builtin_amdgcn_s_setprio(0);
      #pragma unroll
      for (int j = 0; j < 4; ++j) {
        const int q = qb * 16 + g4 * 4 + j;
        attno[((size_t)b * T + q) * D + h * 64 + cb2 * 16 + c0] = f2bf(ao[j]);
      }
    }
  }
}

} // namespace

extern "C" void kernel_launch(void* const* d_in, const int* in_sizes, int n_in,
                              void* d_out, int out_size, void* d_ws, size_t ws_size,
                              hipStream_t stream)
{
  const int*   ipr      = (const int*)d_in[0];
  const int*   isk      = (const int*)d_in[1];
  const float* embP     = (const float*)d_in[2];
  const float* embS     = (const float*)d_in[3];
  const float* mem_init = (const float*)d_in[4];
  const float* pos      = (const float*)d_in[5];
  const float* wqkv     = (const float*)d_in[6];
  const float* bqkv     = (const float*)d_in[7];
  const float* wo       = (const float*)d_in[8];
  const float* bo       = (const float*)d_in[9];
  const float* w1       = (const float*)d_in[10];
  const float* b1       = (const float*)d_in[11];
  const float* w2       = (const float*)d_in[12];
  const float* b2       = (const float*)d_in[13];
  const float* ln_a_g   = (const float*)d_in[14];
  const float* ln_a_b   = (const float*)d_in[15];
  const float* ln_f_g   = (const float*)d_in[16];
  const float* ln_f_b   = (const float*)d_in[17];
  const float* gw       = (const float*)d_in[18];
  const float* gb       = (const float*)d_in[19];
  float* out = (float*)d_out;
  (void)in_sizes; (void)n_in; (void)out_size; (void)ws_size;

  char* ws = (char*)d_ws;
  size_t off = 0;
  auto alloc = [&](size_t bytes) -> void* {
    void* p = ws + off; off += (bytes + 255) & ~(size_t)255; return p;
  };
  unsigned short* wqkv_b = (unsigned short*)alloc((size_t)3072 * 1024 * 2);
  unsigned short* wo_b   = (unsigned short*)alloc((size_t)1024 * 1024 * 2);
  unsigned short* w1_b   = (unsigned short*)alloc((size_t)4096 * 1024 * 2);
  unsigned short* w2_b   = (unsigned short*)alloc((size_t)1024 * 4096 * 2);
  unsigned short* gw_b   = (unsigned short*)alloc((size_t)1024 * 1024 * 2);
  float*          z      = (float*)alloc((size_t)B * T * D * 4);
  unsigned short* zcb    = (unsigned short*)alloc((size_t)B * T * D * 2);
  unsigned short* lnb    = (unsigned short*)alloc((size_t)B * T * D * 2);
  unsigned short* atno   = (unsigned short*)alloc((size_t)B * T * D * 2);
  unsigned short* big    = (unsigned short*)alloc((size_t)B * T * 4096 * 2); // qkv then ffn1
  unsigned short* candb  = (unsigned short*)alloc((size_t)B * MEM * D * 2);
  float*          memb   = (float*)alloc((size_t)B * MEM * D * 4);
  unsigned short* p2     = (unsigned short*)alloc((size_t)2 * B * T * D * 2);   // WO/FFN2 bf16 partials
  unsigned short* p4     = (unsigned short*)alloc((size_t)4 * B * MEM * D * 2); // gate bf16 partials

  k_cvt<<<(3072 * 1024) / 256, 256, 0, stream>>>(wqkv, wqkv_b, 3072 * 1024);
  k_cvt<<<(1024 * 1024) / 256, 256, 0, stream>>>(wo,   wo_b,   1024 * 1024);
  k_cvt<<<(4096 * 1024) / 256, 256, 0, stream>>>(w1,   w1_b,   4096 * 1024);
  k_cvt<<<(1024 * 4096) / 256, 256, 0, stream>>>(w2,   w2_b,   1024 * 4096);
  k_cvt<<<(1024 * 1024) / 256, 256, 0, stream>>>(gw,   gw_b,   1024 * 1024);

  for (int t = 0; t < NC; ++t) {
    k_pre<<<B * T, 256, 0, stream>>>(p4, z, gb, memb, mem_init, pos, embP, embS,
                                     ipr, isk, ln_a_g, ln_a_b, lnb, t);
    // QKV: wide 128x256 tile
    { GArgs a{lnb, wqkv_b, bqkv, big, nullptr, nullptr, nullptr, nullptr, B * T, 3072, 1024, t};
      k_gemmw<0><<<dim3(3072 / 256, (B * T) / 128), 256, 0, stream>>>(a); }
    k_attn<<<B * H, 256, 0, stream>>>(big, atno);
    // WO: split-K=2 bf16 partials; reduce fused into LN_f below
    { GArgs a{atno, wo_b, nullptr, p2, nullptr, nullptr, nullptr, nullptr, B * T, 1024, 1024, t};
      k_gemmp<9, 2><<<dim3(1024 / 128, (B * T) / 128, 2), 256, 0, stream>>>(a); }
    k_ln2<<<(B * T) / 4, 256, 0, stream>>>(ln_f_g, ln_f_b, z, zcb, lnb, p2, bo);
    // FFN1: wide 128x256 tile
    { GArgs a{lnb, w1_b, b1, big, nullptr, nullptr, nullptr, nullptr, B * T, 4096, 1024, t};
      k_gemmw<1><<<dim3(4096 / 256, (B * T) / 128), 256, 0, stream>>>(a); }
    // FFN2: split-K=2 bf16 partials + fused reduce/epilogue
    { GArgs a{big, w2_b, nullptr, p2, nullptr, nullptr, nullptr, nullptr, B * T, 1024, 4096, t};
      k_gemmp<9, 2><<<dim3(1024 / 128, (B * T) / 128, 2), 256, 0, stream>>>(a); }
    k_red2<<<B * T, 256, 0, stream>>>(p2, z, zcb, b2, out, candb, t);
    // gate: split-K=4 bf16 partials (consumed by k_pre next step, or k_redg after loop)
    { GArgs a{candb, gw_b, nullptr, p4, nullptr, nullptr, nullptr, nullptr, B * MEM, 1024, 1024, t};
      k_gemmp<9, 4><<<dim3(1024 / 128, (B * MEM) / 128, 4), 256, 0, stream>>>(a); }
  }
  k_redg<<<B * MEM, 256, 0, stream>>>(p4, z, gb, memb, NC - 1);
  k_copy_mem<<<(B * MEM * D) / 256, 256, 0, stream>>>(memb, out + (size_t)B * L * D);
}

// Round 16
// 4415.471 us; speedup vs baseline: 1.3114x; 1.3114x over previous
//
#include <hip/hip_runtime.h>
#include <cstdint>

typedef __attribute__((ext_vector_type(4))) float f32x4;
typedef __attribute__((ext_vector_type(8))) short s16x8;
typedef __attribute__((ext_vector_type(8))) unsigned short u16x8;
typedef __attribute__((ext_vector_type(4))) unsigned short u16x4;

#define DEVI __device__ __forceinline__

namespace {

constexpr int B = 32, L = 2048, D = 1024, H = 16;
constexpr int CHUNK = 128, MEM = 64, T = 192;
constexpr int NC = 16;

DEVI unsigned short f2bf(float f) {
  unsigned x = __builtin_bit_cast(unsigned, f);
  return (unsigned short)((x + 0x7fffu + ((x >> 16) & 1u)) >> 16);
}
DEVI float bf2f(unsigned short u) {
  return __builtin_bit_cast(float, (unsigned)u << 16);
}

typedef const __attribute__((address_space(1))) unsigned char ga_t;
typedef __attribute__((address_space(3))) unsigned char la_t;

DEVI void gload16(const void* g, void* l) {
  __builtin_amdgcn_global_load_lds((ga_t*)g, (la_t*)l, 16, 0, 0);
}

__global__ void k_cvt(const float* __restrict__ in, unsigned short* __restrict__ out, int n) {
  int i = blockIdx.x * 256 + threadIdx.x;
  if (i < n) out[i] = f2bf(in[i]);
}

__global__ void k_copy_mem(const float* __restrict__ src, float* __restrict__ dst) {
  int i = blockIdx.x * 256 + threadIdx.x;
  dst[i] = src[i];
}

// Unified pre-step kernel: one row per block (grid B*T).
// mem rows:   gate-reduce(step t-1) + mem update (+mem_init at t=0), v = mem + pos
// chunk rows: v = embP + embS + pos
// Then block-LN(v) -> lnb; z <- v.
__global__ __launch_bounds__(256) void k_pre(
    const unsigned short* __restrict__ p4, float* __restrict__ z,
    const float* __restrict__ gb, float* __restrict__ memb,
    const float* __restrict__ mem_init, const float* __restrict__ pos,
    const float* __restrict__ embP, const float* __restrict__ embS,
    const int* __restrict__ ipr, const int* __restrict__ isk,
    const float* __restrict__ gg, const float* __restrict__ bb,
    unsigned short* __restrict__ lnout, int t)
{
  const int row = blockIdx.x;            // 0 .. B*T-1
  const int b = row / T, i = row % T;
  const int tid = threadIdx.x;
  const int c = tid * 4;
  f32x4 v;
  if (i < MEM) {
    const int idx = b * MEM + i;
    f32x4 r;
    if (t == 0) {
      r = *reinterpret_cast<const f32x4*>(&mem_init[(size_t)i * D + c]);
    } else {
      const size_t MN = (size_t)B * MEM * D;
      f32x4 sacc = *reinterpret_cast<const f32x4*>(&gb[c]);
      #pragma unroll
      for (int k = 0; k < 4; ++k) {
        const u16x4 pk = *reinterpret_cast<const u16x4*>(&p4[k * MN + (size_t)idx * D + c]);
        #pragma unroll
        for (int e = 0; e < 4; ++e) sacc[e] += bf2f(pk[e]);
      }
      const f32x4 cand = *reinterpret_cast<const f32x4*>(&z[(size_t)row * D + c]);
      const f32x4 mo   = *reinterpret_cast<const f32x4*>(&memb[(size_t)idx * D + c]);
      #pragma unroll
      for (int e = 0; e < 4; ++e) {
        const float g = 1.0f / (1.0f + __expf(-sacc[e]));
        r[e] = (t - 1 == 0) ? cand[e] : g * cand[e] + (1.0f - g) * mo[e];
      }
    }
    *reinterpret_cast<f32x4*>(&memb[((size_t)b * MEM + i) * D + c]) = r;
    const f32x4 pp = *reinterpret_cast<const f32x4*>(&pos[i * D + c]);
    #pragma unroll
    for (int e = 0; e < 4; ++e) v[e] = r[e] + pp[e];
  } else {
    const int j = t * CHUNK + (i - MEM);
    const int pi = ipr[b * L + j], si = isk[b * L + j];
    const f32x4 ep = *reinterpret_cast<const f32x4*>(&embP[(size_t)pi * D + c]);
    const f32x4 es = *reinterpret_cast<const f32x4*>(&embS[(size_t)si * D + c]);
    const f32x4 pp = *reinterpret_cast<const f32x4*>(&pos[i * D + c]);
    #pragma unroll
    for (int e = 0; e < 4; ++e) v[e] = ep[e] + es[e] + pp[e];
  }
  *reinterpret_cast<f32x4*>(&z[(size_t)row * D + c]) = v;

  float s = v[0] + v[1] + v[2] + v[3];
  float s2 = v[0]*v[0] + v[1]*v[1] + v[2]*v[2] + v[3]*v[3];
  #pragma unroll
  for (int m = 1; m < 64; m <<= 1) { s += __shfl_xor(s, m, 64); s2 += __shfl_xor(s2, m, 64); }
  __shared__ float ps[4], ps2[4];
  const int wid = tid >> 6;
  if ((tid & 63) == 0) { ps[wid] = s; ps2[wid] = s2; }
  __syncthreads();
  s  = ps[0] + ps[1] + ps[2] + ps[3];
  s2 = ps2[0] + ps2[1] + ps2[2] + ps2[3];
  const float mu  = s * (1.0f / 1024.0f);
  const float var = s2 * (1.0f / 1024.0f) - mu * mu;
  const float rs  = rsqrtf(var + 1e-5f);
  u16x4 o;
  #pragma unroll
  for (int e = 0; e < 4; ++e)
    o[e] = f2bf((v[e] - mu) * rs * gg[c + e] + bb[c + e]);
  *reinterpret_cast<u16x4*>(&lnout[(size_t)row * D + c]) = o;
}

// LN_f with WO split-K reduce fused (wave-per-row, 4 rows/block):
// v = z + p0 + p1 + bo; mem rows: z <- v (f32); chunk rows: zcb <- bf16(v).
// LN(v) -> lnb.
__global__ __launch_bounds__(256) void k_ln2(
    const float* __restrict__ gg, const float* __restrict__ bb,
    float* __restrict__ z, unsigned short* __restrict__ zcb,
    unsigned short* __restrict__ lnout,
    const unsigned short* __restrict__ pp, const float* __restrict__ bo)
{
  const int tid = threadIdx.x, lane = tid & 63, wid = tid >> 6;
  const int row = blockIdx.x * 4 + wid;      // 0 .. B*T-1
  const int i = row % T;
  const int c0 = lane * 4;
  const size_t MN = (size_t)B * T * D;

  float v[16];
  #pragma unroll
  for (int k = 0; k < 4; ++k) {
    const int c = k * 256 + c0;
    const f32x4 zz = *reinterpret_cast<const f32x4*>(&z[(size_t)row * D + c]);
    const u16x4 p0 = *reinterpret_cast<const u16x4*>(&pp[(size_t)row * D + c]);
    const u16x4 p1 = *reinterpret_cast<const u16x4*>(&pp[MN + (size_t)row * D + c]);
    const f32x4 bv = *reinterpret_cast<const f32x4*>(&bo[c]);
    #pragma unroll
    for (int e = 0; e < 4; ++e)
      v[k * 4 + e] = zz[e] + bf2f(p0[e]) + bf2f(p1[e]) + bv[e];
  }
  float s = 0.f, s2 = 0.f;
  #pragma unroll
  for (int e = 0; e < 16; ++e) { s += v[e]; s2 += v[e] * v[e]; }
  #pragma unroll
  for (int m = 1; m < 64; m <<= 1) { s += __shfl_xor(s, m, 64); s2 += __shfl_xor(s2, m, 64); }
  const float mu  = s * (1.0f / 1024.0f);
  const float var = s2 * (1.0f / 1024.0f) - mu * mu;
  const float rs  = rsqrtf(var + 1e-5f);
  if (i < MEM) {
    #pragma unroll
    for (int k = 0; k < 4; ++k) {
      f32x4 zz = {v[k*4+0], v[k*4+1], v[k*4+2], v[k*4+3]};
      *reinterpret_cast<f32x4*>(&z[(size_t)row * D + k * 256 + c0]) = zz;
    }
  } else {
    #pragma unroll
    for (int k = 0; k < 4; ++k) {
      const int c = k * 256 + c0;
      u16x4 o;
      #pragma unroll
      for (int e = 0; e < 4; ++e) o[e] = f2bf(v[k * 4 + e]);
      *reinterpret_cast<u16x4*>(&zcb[(size_t)row * D + c]) = o;
    }
  }
  #pragma unroll
  for (int k = 0; k < 4; ++k) {
    const int c = k * 256 + c0;
    u16x4 o;
    #pragma unroll
    for (int e = 0; e < 4; ++e)
      o[e] = f2bf((v[k * 4 + e] - mu) * rs * gg[c + e] + bb[c + e]);
    *reinterpret_cast<u16x4*>(&lnout[(size_t)row * D + c]) = o;
  }
}

struct GArgs {
  const unsigned short* A; const unsigned short* W; const float* bias;
  unsigned short* outb; float* z; float* outf; unsigned short* candb; float* mem;
  int M, N, K, t;
};

// ---- 2-phase dbuf 128x128 bf16 GEMM (proven) ----
// EPI 0: bf16 out   1: relu->bf16   9: bf16 partial store (split-K, no bias)
template<int EPI, int SPLITK>
__global__ __launch_bounds__(256) void k_gemmp(GArgs a)
{
  __shared__ __align__(16) unsigned short Al[2][128 * 32];
  __shared__ __align__(16) unsigned short Bl[2][128 * 32];
  const int tid = threadIdx.x;
  const int lane = tid & 63, wid = tid >> 6;
  const int gx = gridDim.x;
  const int nwg = gx * gridDim.y;
  const int f = blockIdx.y * gx + blockIdx.x;
  const int tile = (f & 7) * (nwg >> 3) + (f >> 3);
  const int brow = (tile / gx) * 128, bcol = (tile % gx) * 128;
  const int wr = wid >> 1, wc = wid & 1;
  const int c0 = lane & 15, g4 = lane >> 4;
  const int K = a.K;
  const int Ks = K / SPLITK;
  const int kbase = blockIdx.z * Ks;

  const int r0 = tid >> 2, oc8 = (tid & 3) * 8;
  const int dst0 = wid * 512, dst1 = 2048 + wid * 512;   // shorts

  f32x4 acc[4][4] = {};

  const unsigned short* __restrict__ Ag = a.A;
  const unsigned short* __restrict__ Wg = a.W;

  auto stage = [&](int t1, int buf) {
    const int kb = kbase + t1 * 32;
    gload16(&Ag[(size_t)(brow + r0) * K + kb + oc8],      &Al[buf][dst0]);
    gload16(&Ag[(size_t)(brow + 64 + r0) * K + kb + oc8], &Al[buf][dst1]);
    gload16(&Wg[(size_t)(bcol + r0) * K + kb + oc8],      &Bl[buf][dst0]);
    gload16(&Wg[(size_t)(bcol + 64 + r0) * K + kb + oc8], &Bl[buf][dst1]);
  };

  stage(0, 0);
  const int nt = Ks >> 5;
  int cur = 0;
  for (int t = 0; t < nt; ++t) {
    __syncthreads();                    // drains vmcnt: buf[cur] ready; buf[cur^1] free
    if (t + 1 < nt) stage(t + 1, cur ^ 1);
    s16x8 af[4], bf[4];
    #pragma unroll
    for (int m = 0; m < 4; ++m)
      af[m] = *reinterpret_cast<const s16x8*>(&Al[cur][(wr * 64 + m * 16 + c0) * 32 + g4 * 8]);
    #pragma unroll
    for (int n = 0; n < 4; ++n)
      bf[n] = *reinterpret_cast<const s16x8*>(&Bl[cur][(wc * 64 + n * 16 + c0) * 32 + g4 * 8]);
    #pragma unroll
    for (int m = 0; m < 4; ++m)
      #pragma unroll
      for (int n = 0; n < 4; ++n)
        acc[m][n] = __builtin_amdgcn_mfma_f32_16x16x32_bf16(af[m], bf[n], acc[m][n], 0, 0, 0);
    cur ^= 1;
  }

  #pragma unroll
  for (int m = 0; m < 4; ++m) {
    #pragma unroll
    for (int n = 0; n < 4; ++n) {
      const int col = bcol + wc * 64 + n * 16 + c0;
      float bv = 0.f;
      if constexpr (EPI != 9) bv = a.bias[col];
      #pragma unroll
      for (int j = 0; j < 4; ++j) {
        const int row = brow + wr * 64 + m * 16 + g4 * 4 + j;
        float v = acc[m][n][j] + bv;
        if constexpr (EPI == 0) {
          a.outb[(size_t)row * a.N + col] = f2bf(v);
        } else if constexpr (EPI == 1) {
          a.outb[(size_t)row * a.N + col] = f2bf(v > 0.f ? v : 0.f);
        } else if constexpr (EPI == 9) {
          a.outb[(size_t)blockIdx.z * a.M * a.N + (size_t)row * a.N + col] = f2bf(v);
        }
      }
    }
  }
}

// FFN2 reduce: v = p0+p1+bias (bf16 partials);
// mem rows: zv = z + v -> z, candb; chunk rows: zv = zcb + v -> d_out.
__global__ __launch_bounds__(256) void k_red2(
    const unsigned short* __restrict__ p, float* __restrict__ z,
    const unsigned short* __restrict__ zcb, const float* __restrict__ bias,
    float* __restrict__ out, unsigned short* __restrict__ candb, int t)
{
  const int row = blockIdx.x;            // 0 .. B*T-1
  const int b = row / T, i = row % T;
  const int c = threadIdx.x * 4;
  const size_t MN = (size_t)B * T * D;
  const u16x4 p0 = *reinterpret_cast<const u16x4*>(&p[(size_t)row * D + c]);
  const u16x4 p1 = *reinterpret_cast<const u16x4*>(&p[MN + (size_t)row * D + c]);
  const f32x4 bb = *reinterpret_cast<const f32x4*>(&bias[c]);
  f32x4 zv;
  if (i < MEM) {
    const f32x4 zz = *reinterpret_cast<const f32x4*>(&z[(size_t)row * D + c]);
    u16x4 o;
    #pragma unroll
    for (int e = 0; e < 4; ++e) {
      zv[e] = zz[e] + bf2f(p0[e]) + bf2f(p1[e]) + bb[e];
      o[e] = f2bf(zv[e]);
    }
    *reinterpret_cast<f32x4*>(&z[(size_t)row * D + c]) = zv;
    *reinterpret_cast<u16x4*>(&candb[((size_t)b * MEM + i) * D + c]) = o;
  } else {
    const u16x4 zz = *reinterpret_cast<const u16x4*>(&zcb[(size_t)row * D + c]);
    #pragma unroll
    for (int e = 0; e < 4; ++e)
      zv[e] = bf2f(zz[e]) + bf2f(p0[e]) + bf2f(p1[e]) + bb[e];
    *reinterpret_cast<f32x4*>(&out[((size_t)b * L + t * CHUNK + (i - MEM)) * D + c]) = zv;
  }
}

// Plain gate reduce (final step only): writes memb.
__global__ __launch_bounds__(256) void k_redg(
    const unsigned short* __restrict__ p, const float* __restrict__ z,
    const float* __restrict__ gb, float* __restrict__ memb, int t)
{
  const int row = blockIdx.x;            // 0 .. B*MEM-1
  const int b = row >> 6, i = row & 63;
  const int c = threadIdx.x * 4;
  const size_t MN = (size_t)B * MEM * D;
  f32x4 s = *reinterpret_cast<const f32x4*>(&gb[c]);
  #pragma unroll
  for (int k = 0; k < 4; ++k) {
    const u16x4 pk = *reinterpret_cast<const u16x4*>(&p[k * MN + (size_t)row * D + c]);
    #pragma unroll
    for (int e = 0; e < 4; ++e) s[e] += bf2f(pk[e]);
  }
  const f32x4 cand = *reinterpret_cast<const f32x4*>(&z[((size_t)b * T + i) * D + c]);
  f32x4 mo = *reinterpret_cast<f32x4*>(&memb[(size_t)row * D + c]);
  f32x4 r;
  #pragma unroll
  for (int e = 0; e < 4; ++e) {
    const float g = 1.0f / (1.0f + __expf(-s[e]));
    r[e] = (t == 0) ? cand[e] : g * cand[e] + (1.0f - g) * mo[e];
  }
  *reinterpret_cast<f32x4*>(&memb[(size_t)row * D + c]) = r;
}

// One workgroup per (b,h). qkv: [B*T][3072] bf16 (q|k|v each H*64 cols).
__global__ __launch_bounds__(256) void k_attn(const unsigned short* __restrict__ qkv,
                                              unsigned short* __restrict__ attno)
{
  __shared__ unsigned short Ks[192 * 64];
  __shared__ unsigned short Vt[64 * 192];
  __shared__ unsigned short Pl[4][16 * 200];
  const int tid = threadIdx.x, lane = tid & 63, wid = tid >> 6;
  const int b = blockIdx.x >> 4, h = blockIdx.x & 15;
  const size_t base = (size_t)b * T * 3072 + h * 64;

  #pragma unroll
  for (int it = 0; it < 6; ++it) {
    const int cidx = tid + it * 256;
    const int key = cidx >> 3, hb = cidx & 7;
    const u16x8 kv = *reinterpret_cast<const u16x8*>(&qkv[base + (size_t)key * 3072 + 1024 + hb * 8]);
    *reinterpret_cast<u16x8*>(&Ks[key * 64 + ((hb ^ (key & 7)) * 8)]) = kv;
    const u16x8 vv = *reinterpret_cast<const u16x8*>(&qkv[base + (size_t)key * 3072 + 2048 + hb * 8]);
    #pragma unroll
    for (int e = 0; e < 8; ++e) {
      const int hd = hb * 8 + e;
      Vt[hd * 192 + (((key >> 3) + hd) % 24) * 8 + (key & 7)] = vv[e];
    }
  }
  __syncthreads();

  const int c0 = lane & 15, g4 = lane >> 4;
  for (int qb = wid; qb < 12; qb += 4) {
    s16x8 qf[2];
    #pragma unroll
    for (int kk = 0; kk < 2; ++kk)
      qf[kk] = *reinterpret_cast<const s16x8*>(&qkv[base + (size_t)(qb * 16 + c0) * 3072 + kk * 32 + g4 * 8]);
    f32x4 sc[12];
    __builtin_amdgcn_s_setprio(1);
    #pragma unroll
    for (int cb = 0; cb < 12; ++cb) {
      f32x4 s4 = {};
      #pragma unroll
      for (int kk = 0; kk < 2; ++kk) {
        const s16x8 kf = *reinterpret_cast<const s16x8*>(
            &Ks[(cb * 16 + c0) * 64 + (((kk * 4 + g4) ^ (c0 & 7)) * 8)]);
        s4 = __builtin_amdgcn_mfma_f32_16x16x32_bf16(qf[kk], kf, s4, 0, 0, 0);
      }
      sc[cb] = s4;
    }
    __builtin_amdgcn_s_setprio(0);
    #pragma unroll
    for (int j = 0; j < 4; ++j) {
      const int qi = qb * 16 + g4 * 4 + j;
      float mj = -1e30f;
      #pragma unroll
      for (int cb = 0; cb < 12; ++cb) {
        const int kj = cb * 16 + c0;
        float sv = sc[cb][j] * 0.125f;
        if (qi >= MEM && kj > qi) sv = -1e30f;
        sc[cb][j] = sv;
        mj = fmaxf(mj, sv);
      }
      #pragma unroll
      for (int msk = 1; msk <= 8; msk <<= 1) mj = fmaxf(mj, __shfl_xor(mj, msk, 64));
      float sum = 0.f;
      #pragma unroll
      for (int cb = 0; cb < 12; ++cb) {
        const float p = exp2f((sc[cb][j] - mj) * 1.44269504f);
        sc[cb][j] = p;
        sum += p;
      }
      #pragma unroll
      for (int msk = 1; msk <= 8; msk <<= 1) sum += __shfl_xor(sum, msk, 64);
      const float rin = 1.0f / sum;
      #pragma unroll
      for (int cb = 0; cb < 12; ++cb)
        Pl[wid][(g4 * 4 + j) * 200 + cb * 16 + c0] = f2bf(sc[cb][j] * rin);
    }
    #pragma unroll
    for (int cb2 = 0; cb2 < 4; ++cb2) {
      f32x4 ao = {};
      const int hd = cb2 * 16 + c0;
      __builtin_amdgcn_s_setprio(1);
      #pragma unroll
      for (int kk = 0; kk < 6; ++kk) {
        const int k0 = kk * 32 + g4 * 8;
        const s16x8 pf = *reinterpret_cast<const s16x8*>(&Pl[wid][c0 * 200 + k0]);
        const s16x8 vf = *reinterpret_cast<const s16x8*>(&Vt[hd * 192 + (((k0 >> 3) + hd) % 24) * 8]);
        ao = __builtin_amdgcn_mfma_f32_16x16x32_bf16(pf, vf, ao, 0, 0, 0);
      }
      __builtin_amdgcn_s_setprio(0);
      #pragma unroll
      for (int j = 0; j < 4; ++j) {
        const int q = qb * 16 + g4 * 4 + j;
        attno[((size_t)b * T + q) * D + h * 64 + cb2 * 16 + c0] = f2bf(ao[j]);
      }
    }
  }
}

} // namespace

extern "C" void kernel_launch(void* const* d_in, const int* in_sizes, int n_in,
                              void* d_out, int out_size, void* d_ws, size_t ws_size,
                              hipStream_t stream)
{
  const int*   ipr      = (const int*)d_in[0];
  const int*   isk      = (const int*)d_in[1];
  const float* embP     = (const float*)d_in[2];
  const float* embS     = (const float*)d_in[3];
  const float* mem_init = (const float*)d_in[4];
  const float* pos      = (const float*)d_in[5];
  const float* wqkv     = (const float*)d_in[6];
  const float* bqkv     = (const float*)d_in[7];
  const float* wo       = (const float*)d_in[8];
  const float* bo       = (const float*)d_in[9];
  const float* w1       = (const float*)d_in[10];
  const float* b1       = (const float*)d_in[11];
  const float* w2       = (const float*)d_in[12];
  const float* b2       = (const float*)d_in[13];
  const float* ln_a_g   = (const float*)d_in[14];
  const float* ln_a_b   = (const float*)d_in[15];
  const float* ln_f_g   = (const float*)d_in[16];
  const float* ln_f_b   = (const float*)d_in[17];
  const float* gw       = (const float*)d_in[18];
  const float* gb       = (const float*)d_in[19];
  float* out = (float*)d_out;
  (void)in_sizes; (void)n_in; (void)out_size; (void)ws_size;

  char* ws = (char*)d_ws;
  size_t off = 0;
  auto alloc = [&](size_t bytes) -> void* {
    void* p = ws + off; off += (bytes + 255) & ~(size_t)255; return p;
  };
  unsigned short* wqkv_b = (unsigned short*)alloc((size_t)3072 * 1024 * 2);
  unsigned short* wo_b   = (unsigned short*)alloc((size_t)1024 * 1024 * 2);
  unsigned short* w1_b   = (unsigned short*)alloc((size_t)4096 * 1024 * 2);
  unsigned short* w2_b   = (unsigned short*)alloc((size_t)1024 * 4096 * 2);
  unsigned short* gw_b   = (unsigned short*)alloc((size_t)1024 * 1024 * 2);
  float*          z      = (float*)alloc((size_t)B * T * D * 4);
  unsigned short* zcb    = (unsigned short*)alloc((size_t)B * T * D * 2);
  unsigned short* lnb    = (unsigned short*)alloc((size_t)B * T * D * 2);
  unsigned short* atno   = (unsigned short*)alloc((size_t)B * T * D * 2);
  unsigned short* big    = (unsigned short*)alloc((size_t)B * T * 4096 * 2); // qkv then ffn1
  unsigned short* candb  = (unsigned short*)alloc((size_t)B * MEM * D * 2);
  float*          memb   = (float*)alloc((size_t)B * MEM * D * 4);
  unsigned short* p2     = (unsigned short*)alloc((size_t)2 * B * T * D * 2);   // WO/FFN2 bf16 partials
  unsigned short* p4     = (unsigned short*)alloc((size_t)4 * B * MEM * D * 2); // gate bf16 partials

  k_cvt<<<(3072 * 1024) / 256, 256, 0, stream>>>(wqkv, wqkv_b, 3072 * 1024);
  k_cvt<<<(1024 * 1024) / 256, 256, 0, stream>>>(wo,   wo_b,   1024 * 1024);
  k_cvt<<<(4096 * 1024) / 256, 256, 0, stream>>>(w1,   w1_b,   4096 * 1024);
  k_cvt<<<(1024 * 4096) / 256, 256, 0, stream>>>(w2,   w2_b,   1024 * 4096);
  k_cvt<<<(1024 * 1024) / 256, 256, 0, stream>>>(gw,   gw_b,   1024 * 1024);

  for (int t = 0; t < NC; ++t) {
    k_pre<<<B * T, 256, 0, stream>>>(p4, z, gb, memb, mem_init, pos, embP, embS,
                                     ipr, isk, ln_a_g, ln_a_b, lnb, t);
    { GArgs a{lnb, wqkv_b, bqkv, big, nullptr, nullptr, nullptr, nullptr, B * T, 3072, 1024, t};
      k_gemmp<0, 1><<<dim3(3072 / 128, (B * T) / 128), 256, 0, stream>>>(a); }
    k_attn<<<B * H, 256, 0, stream>>>(big, atno);
    // WO: split-K=2 bf16 partials; reduce fused into LN_f below
    { GArgs a{atno, wo_b, nullptr, p2, nullptr, nullptr, nullptr, nullptr, B * T, 1024, 1024, t};
      k_gemmp<9, 2><<<dim3(1024 / 128, (B * T) / 128, 2), 256, 0, stream>>>(a); }
    k_ln2<<<(B * T) / 4, 256, 0, stream>>>(ln_f_g, ln_f_b, z, zcb, lnb, p2, bo);
    { GArgs a{lnb, w1_b, b1, big, nullptr, nullptr, nullptr, nullptr, B * T, 4096, 1024, t};
      k_gemmp<1, 1><<<dim3(4096 / 128, (B * T) / 128), 256, 0, stream>>>(a); }
    // FFN2: split-K=2 bf16 partials + fused reduce/epilogue
    { GArgs a{big, w2_b, nullptr, p2, nullptr, nullptr, nullptr, nullptr, B * T, 1024, 4096, t};
      k_gemmp<9, 2><<<dim3(1024 / 128, (B * T) / 128, 2), 256, 0, stream>>>(a); }
    k_red2<<<B * T, 256, 0, stream>>>(p2, z, zcb, b2, out, candb, t);
    // gate: split-K=4 bf16 partials (consumed by k_pre next step, or k_redg after loop)
    { GArgs a{candb, gw_b, nullptr, p4, nullptr, nullptr, nullptr, nullptr, B * MEM, 1024, 1024, t};
      k_gemmp<9, 4><<<dim3(1024 / 128, (B * MEM) / 128, 4), 256, 0, stream>>>(a); }
  }
  k_redg<<<B * MEM, 256, 0, stream>>>(p4, z, gb, memb, NC - 1);
  k_copy_mem<<<(B * MEM * D) / 256, 256, 0, stream>>>(memb, out + (size_t)B * L * D);
}